// Round 1
// baseline (285.587 us; speedup 1.0000x reference)
//
#include <hip/hip_runtime.h>
#include <stdint.h>

#define NB 8
#define NS 256
#define ND 1024
#define EPSF 1e-5f

typedef __attribute__((ext_vector_type(8))) short short8;
typedef __attribute__((ext_vector_type(4))) float f32x4;

__device__ __forceinline__ unsigned short f2bf(float f) {
  unsigned int u = __float_as_uint(f);
  u = (u + 0x7FFFu + ((u >> 16) & 1u)) >> 16;
  return (unsigned short)u;
}

// ---------------- fp32 -> bf16 convert ----------------
__global__ __launch_bounds__(256) void k_convert(const float* __restrict__ x,
                                                 unsigned short* __restrict__ xb, int n4) {
  int idx = blockIdx.x * blockDim.x + threadIdx.x;
  int stride = gridDim.x * blockDim.x;
  for (int i = idx; i < n4; i += stride) {
    float4 v = reinterpret_cast<const float4*>(x)[i];
    ushort4 o;
    o.x = f2bf(v.x); o.y = f2bf(v.y); o.z = f2bf(v.z); o.w = f2bf(v.w);
    reinterpret_cast<ushort4*>(xb)[i] = o;
  }
}

// ---------------- G = X X^T (bf16 MFMA, K-split 4, partials) ----------------
// wave job: 32x32 output tile, K=256 slice. frag: row = lane&15, k = (lane>>4)*8 + e
__global__ __launch_bounds__(256) void k_gemm(const unsigned short* __restrict__ xb,
                                              float* __restrict__ gp) {
  int gw = ((blockIdx.x << 8) + threadIdx.x) >> 6;  // 0..2047
  int lane = threadIdx.x & 63;
  int b  = gw & 7;
  int mt = (gw >> 3) & 7;
  int nt = (gw >> 6) & 7;
  int ks = gw >> 9;  // 0..3
  const unsigned short* Ab = xb + ((size_t)b << 18) + ((size_t)(mt << 5) << 10);
  const unsigned short* Bb = xb + ((size_t)b << 18) + ((size_t)(nt << 5) << 10);
  int lr = lane & 15;
  int lk = (lane >> 4) << 3;
  f32x4 acc00 = {0.f,0.f,0.f,0.f}, acc01 = {0.f,0.f,0.f,0.f};
  f32x4 acc10 = {0.f,0.f,0.f,0.f}, acc11 = {0.f,0.f,0.f,0.f};
  int kbase = (ks << 8) + lk;
#pragma unroll 2
  for (int kk = 0; kk < 256; kk += 32) {
    int ko = kbase + kk;
    short8 a0  = *reinterpret_cast<const short8*>(Ab + ((size_t)lr << 10) + ko);
    short8 a1  = *reinterpret_cast<const short8*>(Ab + ((size_t)(16 + lr) << 10) + ko);
    short8 bb0 = *reinterpret_cast<const short8*>(Bb + ((size_t)lr << 10) + ko);
    short8 bb1 = *reinterpret_cast<const short8*>(Bb + ((size_t)(16 + lr) << 10) + ko);
    acc00 = __builtin_amdgcn_mfma_f32_16x16x32_bf16(a0, bb0, acc00, 0, 0, 0);
    acc01 = __builtin_amdgcn_mfma_f32_16x16x32_bf16(a0, bb1, acc01, 0, 0, 0);
    acc10 = __builtin_amdgcn_mfma_f32_16x16x32_bf16(a1, bb0, acc10, 0, 0, 0);
    acc11 = __builtin_amdgcn_mfma_f32_16x16x32_bf16(a1, bb1, acc11, 0, 0, 0);
  }
  // C/D layout: col = lane&15, row = (lane>>4)*4 + j   [measured m89]
  float* G = gp + (size_t)ks * (NB * NS * NS) + (size_t)b * NS * NS;
  int r0 = (mt << 5) + ((lane >> 4) << 2);
  int c0 = (nt << 5) + lr;
#pragma unroll
  for (int j = 0; j < 4; ++j) {
    G[(r0 + j) * NS + c0]           = acc00[j];
    G[(r0 + j) * NS + c0 + 16]      = acc01[j];
    G[(r0 + 16 + j) * NS + c0]      = acc10[j];
    G[(r0 + 16 + j) * NS + c0 + 16] = acc11[j];
  }
}

// ---------------- reduce partials + row-prefix C, diag, CD, inv_xnorm ----------------
__global__ __launch_bounds__(64) void k_prefix(const float* __restrict__ gp, float* __restrict__ C,
                                               float* __restrict__ CDa, float* __restrict__ DGa,
                                               float* __restrict__ IXa) {
  int b = blockIdx.x >> 2;
  int t = ((blockIdx.x & 3) << 6) + threadIdx.x;
  const float* g = gp + (size_t)b * NS * NS;
  const int NP = NB * NS * NS;
  float* Cb = C + (size_t)b * 257 * NS;
  float run = 0.f, mycd = 0.f, mydg = 0.f;
  Cb[t] = 0.f;
  for (int j = 0; j < NS; ++j) {
    int o = j * NS + t;
    float gv = g[o] + g[NP + o] + g[2 * NP + o] + g[3 * NP + o];
    if (j == t) { mycd = run; mydg = gv; }
    run += gv;
    Cb[(j + 1) * NS + t] = run;
  }
  CDa[b * NS + t] = mycd;                 // C[t,t] = sum_{s<t} G[s,t]
  DGa[b * NS + t] = mydg;                 // G[t,t]
  float xn = sqrtf(fmaxf(mydg, 0.f));
  IXa[b * NS + t] = 1.0f / xn;            // inf if xnorm==0 -> forces slow path
}

// ---------------- worst = min_t cos, one wave per (b,i) ----------------
__global__ __launch_bounds__(256) void k_worst(const float* __restrict__ C,
                                               const float* __restrict__ CDa,
                                               const float* __restrict__ DGa,
                                               const float* __restrict__ IXa,
                                               float* __restrict__ out) {
  int lane = threadIdx.x & 63;
  int wv = threadIdx.x >> 6;
  int b = blockIdx.x & 7;
  int i4 = blockIdx.x >> 3;                       // 0..63, heavy (small i) first
  int i = ((i4 & 31) << 2) + wv + ((i4 & 32) ? 128 : 0);  // SIMD pairs {i, i+128}
  if (i == 0) return;                              // row 0 invalid -> stays zero
  const float* Cb = C + (size_t)b * 257 * NS;
  const float* CDb = CDa + b * NS;
  const float* DGb = DGa + b * NS;
  const float* IXb = IXa + b * NS;

  // per-lane preload of C[i, t] and inv_xnorm[t] for t = i + chunk*64 + lane
  float base0, base1, base2, base3, w0, w1, w2, w3;
  {
    int t0 = i + lane;        int c0 = t0 < NS ? t0 : NS - 1; bool ok0 = t0 < NS;
    int t1 = t0 + 64;         int c1 = t1 < NS ? t1 : NS - 1; bool ok1 = t1 < NS;
    int t2 = t0 + 128;        int c2 = t2 < NS ? t2 : NS - 1; bool ok2 = t2 < NS;
    int t3 = t0 + 192;        int c3 = t3 < NS ? t3 : NS - 1; bool ok3 = t3 < NS;
    const float* ri = Cb + i * NS;
    base0 = ok0 ? ri[c0] : 0.f;  w0 = ok0 ? IXb[c0] : 0.f;
    base1 = ok1 ? ri[c1] : 0.f;  w1 = ok1 ? IXb[c1] : 0.f;
    base2 = ok2 ? ri[c2] : 0.f;  w2 = ok2 ? IXb[c2] : 0.f;
    base3 = ok3 ? ri[c3] : 0.f;  w3 = ok3 ? IXb[c3] : 0.f;
  }
  float wm = fmaxf(fmaxf(w0, w1), fmaxf(w2, w3));
#pragma unroll
  for (int off = 32; off; off >>= 1) wm = fmaxf(wm, __shfl_xor(wm, off));

  float ssq = 0.f;
  float* orow = out + ((size_t)b << 16) + (size_t)i * NS;
  for (int j = i; j < NS; ++j) {
    int d = j - i;
    const float* rj = Cb + (j + 1) * NS;
    float m = 3.0e38f;
    { int t = i + lane;       int tc = t < NS ? t : NS - 1; float v = (rj[tc] - base0) * w0; if (lane <= d)       m = fminf(m, v); }
    if (d >= 64)  { int t = i + 64 + lane;  int tc = t < NS ? t : NS - 1; float v = (rj[tc] - base1) * w1; if (lane <= d - 64)  m = fminf(m, v); }
    if (d >= 128) { int t = i + 128 + lane; int tc = t < NS ? t : NS - 1; float v = (rj[tc] - base2) * w2; if (lane <= d - 128) m = fminf(m, v); }
    if (d >= 192) { int t = i + 192 + lane; int tc = t < NS ? t : NS - 1; float v = (rj[tc] - base3) * w3; if (lane <= d - 192) m = fminf(m, v); }
#pragma unroll
    for (int off = 32; off; off >>= 1) m = fminf(m, __shfl_xor(m, off));

    // ssq(i,j) = ssq(i,j-1) + 2*(C[j,j] - C[i,j]) + G[j,j]   (uniform loads)
    float bj  = Cb[i * NS + j];
    float cdj = CDb[j];
    float dgj = DGb[j];
    ssq = ssq + 2.f * (cdj - bj) + dgj;
    float sn = sqrtf(fmaxf(ssq, 0.f));
    float win = (float)(d + 1);
    float res;
    if (sn >= EPSF * win * wm) {
      res = m / sn;                                   // fast path (EPS never binds)
    } else {
      float invwin = 1.0f / win;
      float mn = sn * invwin;                         // mean_norm
      float mm = 3.0e38f;
      { int t = i + lane;       int tc = t < NS ? t : NS - 1; float num = rj[tc] - base0; float den = fmaxf(mn * (1.0f / w0), EPSF); float v = num * invwin / den; if (lane <= d)       mm = fminf(mm, v); }
      if (d >= 64)  { int t = i + 64 + lane;  int tc = t < NS ? t : NS - 1; float num = rj[tc] - base1; float den = fmaxf(mn * (1.0f / w1), EPSF); float v = num * invwin / den; if (lane <= d - 64)  mm = fminf(mm, v); }
      if (d >= 128) { int t = i + 128 + lane; int tc = t < NS ? t : NS - 1; float num = rj[tc] - base2; float den = fmaxf(mn * (1.0f / w2), EPSF); float v = num * invwin / den; if (lane <= d - 128) mm = fminf(mm, v); }
      if (d >= 192) { int t = i + 192 + lane; int tc = t < NS ? t : NS - 1; float num = rj[tc] - base3; float den = fmaxf(mn * (1.0f / w3), EPSF); float v = num * invwin / den; if (lane <= d - 192) mm = fminf(mm, v); }
#pragma unroll
      for (int off = 32; off; off >>= 1) mm = fminf(mm, __shfl_xor(mm, off));
      res = mm;
    }
    if (j > i && lane == 0) orow[j] = res;
  }
}

extern "C" void kernel_launch(void* const* d_in, const int* in_sizes, int n_in,
                              void* d_out, int out_size, void* d_ws, size_t ws_size,
                              hipStream_t stream) {
  (void)in_sizes; (void)n_in; (void)ws_size;
  const float* x = (const float*)d_in[0];
  float* out = (float*)d_out;
  char* ws = (char*)d_ws;
  unsigned short* Xb = (unsigned short*)(ws);                       // 4,194,304 B
  float* Gp  = (float*)(ws + 4194304);                              // 8,388,608 B
  float* C   = (float*)(ws + 4194304 + 8388608);                    // 2,105,344 B
  float* CDa = (float*)(ws + 4194304 + 8388608 + 2105344);          // 8,192 B
  float* DGa = CDa + NB * NS;                                       // 8,192 B
  float* IXa = DGa + NB * NS;                                       // 8,192 B

  hipMemsetAsync(d_out, 0, (size_t)out_size * sizeof(float), stream);
  k_convert<<<1024, 256, 0, stream>>>(x, Xb, (NB * NS * ND) / 4);
  k_gemm<<<512, 256, 0, stream>>>(Xb, Gp);
  k_prefix<<<32, 64, 0, stream>>>(Gp, C, CDa, DGa, IXa);
  k_worst<<<512, 256, 0, stream>>>(C, CDa, DGa, IXa, out);
}

// Round 2
// 127.281 us; speedup vs baseline: 2.2438x; 2.2438x over previous
//
#include <hip/hip_runtime.h>
#include <stdint.h>

#define NB 8
#define NS 256
#define ND 1024
#define EPSF 1e-5f
#define BIGF 3.0e38f

typedef __attribute__((ext_vector_type(8))) short short8;
typedef __attribute__((ext_vector_type(4))) float f32x4;

__device__ __forceinline__ unsigned short f2bf(float f) {
  unsigned int u = __float_as_uint(f);
  u = (u + 0x7FFFu + ((u >> 16) & 1u)) >> 16;
  return (unsigned short)u;
}

// ---------------- fp32 -> bf16 convert ----------------
__global__ __launch_bounds__(256) void k_convert(const float* __restrict__ x,
                                                 unsigned short* __restrict__ xb, int n4) {
  int idx = blockIdx.x * blockDim.x + threadIdx.x;
  int stride = gridDim.x * blockDim.x;
  for (int i = idx; i < n4; i += stride) {
    float4 v = reinterpret_cast<const float4*>(x)[i];
    ushort4 o;
    o.x = f2bf(v.x); o.y = f2bf(v.y); o.z = f2bf(v.z); o.w = f2bf(v.w);
    reinterpret_cast<ushort4*>(xb)[i] = o;
  }
}

// ---------------- G = X X^T (bf16 MFMA, K-split 4, partials) ----------------
__global__ __launch_bounds__(256) void k_gemm(const unsigned short* __restrict__ xb,
                                              float* __restrict__ gp) {
  int gw = ((blockIdx.x << 8) + threadIdx.x) >> 6;  // 0..2047
  int lane = threadIdx.x & 63;
  int b  = gw & 7;
  int mt = (gw >> 3) & 7;
  int nt = (gw >> 6) & 7;
  int ks = gw >> 9;  // 0..3
  const unsigned short* Ab = xb + ((size_t)b << 18) + ((size_t)(mt << 5) << 10);
  const unsigned short* Bb = xb + ((size_t)b << 18) + ((size_t)(nt << 5) << 10);
  int lr = lane & 15;
  int lk = (lane >> 4) << 3;
  f32x4 acc00 = {0.f,0.f,0.f,0.f}, acc01 = {0.f,0.f,0.f,0.f};
  f32x4 acc10 = {0.f,0.f,0.f,0.f}, acc11 = {0.f,0.f,0.f,0.f};
  int kbase = (ks << 8) + lk;
#pragma unroll 2
  for (int kk = 0; kk < 256; kk += 32) {
    int ko = kbase + kk;
    short8 a0  = *reinterpret_cast<const short8*>(Ab + ((size_t)lr << 10) + ko);
    short8 a1  = *reinterpret_cast<const short8*>(Ab + ((size_t)(16 + lr) << 10) + ko);
    short8 bb0 = *reinterpret_cast<const short8*>(Bb + ((size_t)lr << 10) + ko);
    short8 bb1 = *reinterpret_cast<const short8*>(Bb + ((size_t)(16 + lr) << 10) + ko);
    acc00 = __builtin_amdgcn_mfma_f32_16x16x32_bf16(a0, bb0, acc00, 0, 0, 0);
    acc01 = __builtin_amdgcn_mfma_f32_16x16x32_bf16(a0, bb1, acc01, 0, 0, 0);
    acc10 = __builtin_amdgcn_mfma_f32_16x16x32_bf16(a1, bb0, acc10, 0, 0, 0);
    acc11 = __builtin_amdgcn_mfma_f32_16x16x32_bf16(a1, bb1, acc11, 0, 0, 0);
  }
  // C/D layout: col = lane&15, row = (lane>>4)*4 + j   [measured m89]
  float* G = gp + (size_t)ks * (NB * NS * NS) + (size_t)b * NS * NS;
  int r0 = (mt << 5) + ((lane >> 4) << 2);
  int c0 = (nt << 5) + lr;
#pragma unroll
  for (int j = 0; j < 4; ++j) {
    G[(r0 + j) * NS + c0]           = acc00[j];
    G[(r0 + j) * NS + c0 + 16]      = acc01[j];
    G[(r0 + 16 + j) * NS + c0]      = acc10[j];
    G[(r0 + 16 + j) * NS + c0 + 16] = acc11[j];
  }
}

// ---------------- reduce partials + row-prefix C, diag G, inv_xnorm ----------------
__global__ __launch_bounds__(64) void k_prefix(const float* __restrict__ gp, float* __restrict__ C,
                                               float* __restrict__ DGa, float* __restrict__ IXa) {
  int b = blockIdx.x >> 2;
  int t = ((blockIdx.x & 3) << 6) + threadIdx.x;
  const float* g = gp + (size_t)b * NS * NS;
  const int NP = NB * NS * NS;
  float* Cb = C + (size_t)b * 257 * NS;
  float run = 0.f, mydg = 0.f;
  Cb[t] = 0.f;
  for (int j = 0; j < NS; ++j) {
    int o = j * NS + t;
    float gv = g[o] + g[NP + o] + g[2 * NP + o] + g[3 * NP + o];
    if (j == t) mydg = gv;
    run += gv;
    Cb[(j + 1) * NS + t] = run;
  }
  DGa[b * NS + t] = mydg;                 // G[t,t]
  float xn = sqrtf(fmaxf(mydg, 0.f));
  IXa[b * NS + t] = 1.0f / xn;            // inf if xnorm==0 -> forces slow path
}

// ---------------- S2[r,c] = sum_{t<c} C[r,t]  (row prefix scan, 1 wave/row) ----------------
__global__ __launch_bounds__(256) void k_scan(const float* __restrict__ C, float* __restrict__ S2) {
  int id = blockIdx.x * 4 + (threadIdx.x >> 6);   // 0..2055
  int lane = threadIdx.x & 63;
  int b = id / 257;
  int r = id - b * 257;
  const float* Crow = C + ((size_t)b * 257 + r) * NS;
  float* Srow = S2 + ((size_t)b * 257 + r) * 257;
  if (lane == 0) Srow[0] = 0.f;
  float run = 0.f;
  for (int c0 = 0; c0 < NS; c0 += 64) {
    float v = Crow[c0 + lane];
#pragma unroll
    for (int off = 1; off < 64; off <<= 1) {
      float n = __shfl_up(v, off);
      if (lane >= off) v += n;
    }
    Srow[c0 + lane + 1] = run + v;
    run += __shfl(v, 63);
  }
}

// ---------------- per-batch max of inv_xnorm ----------------
__global__ __launch_bounds__(64) void k_wmax(const float* __restrict__ IXa, float* __restrict__ WM) {
  int b = blockIdx.x;
  int lane = threadIdx.x;
  const float* IXb = IXa + b * NS;
  float m = 0.f;
#pragma unroll
  for (int k = 0; k < 4; ++k) m = fmaxf(m, IXb[k * 64 + lane]);
#pragma unroll
  for (int off = 32; off; off >>= 1) m = fmaxf(m, __shfl_xor(m, off));
  if (lane == 0) WM[b] = m;
}

// ---------------- tropical GEMM: worst[i,j] = min_t (W[j+1,t]-W[i,t]) / sn(i,j) ----------------
// tiles: 32 i-rows x 64 j-cols, t staged in 64-chunks via LDS (t-major, W = C * invxnorm)
static __device__ const unsigned char kTi[20] = {0,0,0,0,1,1,1,1,2,2,2,3,3,3,4,4,5,5,6,7};
static __device__ const unsigned char kTj[20] = {0,1,2,3,0,1,2,3,1,2,3,1,2,3,2,3,2,3,3,3};

__global__ __launch_bounds__(256) void k_trop(const float* __restrict__ C,
                                              const float* __restrict__ S2,
                                              const float* __restrict__ IXa,
                                              const float* __restrict__ DGa,
                                              const float* __restrict__ WM,
                                              float* __restrict__ out) {
  __shared__ float As[64][36];   // As[tt][ii]  (i-tile 32 rows, pad->stride 36)
  __shared__ float Bs[64][68];   // Bs[tt][jj]  (j-tile 64 rows, pad->stride 68)
  int blk = blockIdx.x;
  int b = blk / 20;
  int tix = blk - b * 20;
  int i0 = (int)kTi[tix] * 32;
  int j0 = (int)kTj[tix] * 64;
  int tid = threadIdx.x;
  int ii0 = (tid >> 4) << 1;     // 0,2,...,30
  int jj0 = (tid & 15) << 2;     // 0,4,...,60
  const float* Cb = C + (size_t)b * 257 * NS;
  const float* IXb = IXa + b * NS;
  float acc[8];
#pragma unroll
  for (int k = 0; k < 8; ++k) acc[k] = BIGF;

  int rA = tid >> 4;             // staging row helper 0..15
  int c4 = (tid & 15) << 2;      // staging col 0..60

  for (int t0 = i0 & ~63; t0 < j0 + 64; t0 += 64) {
    __syncthreads();
    float4 wv = *reinterpret_cast<const float4*>(IXb + t0 + c4);
#pragma unroll
    for (int p = 0; p < 2; ++p) {      // A: rows i0..i0+31
      int r = i0 + p * 16 + rA;
      float4 v = *reinterpret_cast<const float4*>(Cb + (size_t)r * NS + t0 + c4);
      As[c4 + 0][p * 16 + rA] = v.x * wv.x;
      As[c4 + 1][p * 16 + rA] = v.y * wv.y;
      As[c4 + 2][p * 16 + rA] = v.z * wv.z;
      As[c4 + 3][p * 16 + rA] = v.w * wv.w;
    }
#pragma unroll
    for (int p = 0; p < 4; ++p) {      // B: rows j0+1..j0+64
      int r = j0 + 1 + p * 16 + rA;
      float4 v = *reinterpret_cast<const float4*>(Cb + (size_t)r * NS + t0 + c4);
      Bs[c4 + 0][p * 16 + rA] = v.x * wv.x;
      Bs[c4 + 1][p * 16 + rA] = v.y * wv.y;
      Bs[c4 + 2][p * 16 + rA] = v.z * wv.z;
      Bs[c4 + 3][p * 16 + rA] = v.w * wv.w;
    }
    __syncthreads();

    int thA = i0 + ii0 - t0;   // a[k] valid iff tt >= thA + k
    int thB = j0 + jj0 - t0;   // b[l] valid iff tt <= thB + l
    if (thA <= -1 && thB >= 63) {
      // fully interior: no masking
#pragma unroll 4
      for (int tt = 0; tt < 64; ++tt) {
        float2 a = *reinterpret_cast<const float2*>(&As[tt][ii0]);
        float4 bv = *reinterpret_cast<const float4*>(&Bs[tt][jj0]);
        acc[0] = fminf(acc[0], bv.x - a.x);
        acc[1] = fminf(acc[1], bv.y - a.x);
        acc[2] = fminf(acc[2], bv.z - a.x);
        acc[3] = fminf(acc[3], bv.w - a.x);
        acc[4] = fminf(acc[4], bv.x - a.y);
        acc[5] = fminf(acc[5], bv.y - a.y);
        acc[6] = fminf(acc[6], bv.z - a.y);
        acc[7] = fminf(acc[7], bv.w - a.y);
      }
    } else {
#pragma unroll 4
      for (int tt = 0; tt < 64; ++tt) {
        float2 a = *reinterpret_cast<const float2*>(&As[tt][ii0]);
        float4 bv = *reinterpret_cast<const float4*>(&Bs[tt][jj0]);
        float a0 = (tt >= thA)     ? a.x  : -BIGF;
        float a1 = (tt >= thA + 1) ? a.y  : -BIGF;
        float b0 = (tt <= thB)     ? bv.x :  BIGF;
        float b1 = (tt <= thB + 1) ? bv.y :  BIGF;
        float b2 = (tt <= thB + 2) ? bv.z :  BIGF;
        float b3 = (tt <= thB + 3) ? bv.w :  BIGF;
        acc[0] = fminf(acc[0], b0 - a0);
        acc[1] = fminf(acc[1], b1 - a0);
        acc[2] = fminf(acc[2], b2 - a0);
        acc[3] = fminf(acc[3], b3 - a0);
        acc[4] = fminf(acc[4], b0 - a1);
        acc[5] = fminf(acc[5], b1 - a1);
        acc[6] = fminf(acc[6], b2 - a1);
        acc[7] = fminf(acc[7], b3 - a1);
      }
    }
  }

  // epilogue: divide by segment norm, handle EPS slow path, store valid cells
  const float* S2b = S2 + (size_t)b * 257 * 257;
  const float* DGb = DGa + b * NS;
  float wmb = WM[b];
  float* outb = out + ((size_t)b << 16);
#pragma unroll
  for (int k = 0; k < 2; ++k) {
    int i = i0 + ii0 + k;
    if (i < 1) continue;
    float s2ii = S2b[(size_t)i * 257 + i];
#pragma unroll
    for (int l = 0; l < 4; ++l) {
      int j = j0 + jj0 + l;
      if (j <= i) continue;
      float s2jj = S2b[(size_t)(j + 1) * 257 + (j + 1)];
      float s2ij = S2b[(size_t)i * 257 + (j + 1)];
      float s2ji = S2b[(size_t)(j + 1) * 257 + i];
      float ssq = (s2jj - s2ij) - (s2ji - s2ii);
      float sn = sqrtf(fmaxf(ssq, 0.f));
      float win = (float)(j - i + 1);
      float res;
      if (sn >= EPSF * win * wmb) {
        res = acc[k * 4 + l] / sn;                 // fast path: EPS never binds
      } else {
        float mn = sn / win;
        float m = BIGF;
        const float* r2 = Cb + (size_t)(j + 1) * NS;
        const float* r1 = Cb + (size_t)i * NS;
        for (int t = i; t <= j; ++t) {
          float num = r2[t] - r1[t];
          float xn = sqrtf(fmaxf(DGb[t], 0.f));
          float den = fmaxf(mn * xn, EPSF);
          m = fminf(m, num / win / den);
        }
        res = m;
      }
      outb[(size_t)i * NS + j] = res;
    }
  }
}

extern "C" void kernel_launch(void* const* d_in, const int* in_sizes, int n_in,
                              void* d_out, int out_size, void* d_ws, size_t ws_size,
                              hipStream_t stream) {
  (void)in_sizes; (void)n_in; (void)ws_size;
  const float* x = (const float*)d_in[0];
  float* out = (float*)d_out;
  char* ws = (char*)d_ws;
  unsigned short* Xb = (unsigned short*)(ws);                 //  4,194,304 B
  float* Gp  = (float*)(ws + 4194304);                        //  8,388,608 B
  float* C   = (float*)(ws + 12582912);                       //  2,105,344 B (8 x 257 x 256)
  float* S2  = (float*)(ws + 14688256);                       //  2,113,568 B (8 x 257 x 257)
  float* DGa = (float*)(ws + 16801824);                       //  8,192 B
  float* IXa = (float*)(ws + 16810016);                       //  8,192 B
  float* WM  = (float*)(ws + 16818208);                       //  32 B

  hipMemsetAsync(d_out, 0, (size_t)out_size * sizeof(float), stream);
  k_convert<<<1024, 256, 0, stream>>>(x, Xb, (NB * NS * ND) / 4);
  k_gemm<<<512, 256, 0, stream>>>(Xb, Gp);
  k_prefix<<<32, 64, 0, stream>>>(Gp, C, DGa, IXa);
  k_scan<<<514, 256, 0, stream>>>(C, S2);
  k_wmax<<<8, 64, 0, stream>>>(IXa, WM);
  k_trop<<<160, 256, 0, stream>>>(C, S2, IXa, DGa, WM, out);
}

// Round 3
// 113.125 us; speedup vs baseline: 2.5245x; 1.1251x over previous
//
#include <hip/hip_runtime.h>
#include <stdint.h>

#define NB 8
#define NS 256
#define ND 1024
#define EPSF 1e-5f
#define BIGF 3.0e38f

typedef __attribute__((ext_vector_type(8))) short short8;
typedef __attribute__((ext_vector_type(4))) float f32x4;

__device__ __forceinline__ unsigned short f2bf(float f) {
  unsigned int u = __float_as_uint(f);
  u = (u + 0x7FFFu + ((u >> 16) & 1u)) >> 16;
  return (unsigned short)u;
}
__device__ __forceinline__ float bf2f(unsigned short u) {
  return __uint_as_float((unsigned int)u << 16);
}

// ---- fp32 -> bf16 convert, fused exact diag ||x_t||^2 and inv_xnorm ----
// one wave per row (b,s): 2048 rows
__global__ __launch_bounds__(256) void k_convert(const float* __restrict__ x,
                                                 unsigned short* __restrict__ xb,
                                                 float* __restrict__ DGa,
                                                 float* __restrict__ IXa) {
  int row = blockIdx.x * 4 + (threadIdx.x >> 6);
  int lane = threadIdx.x & 63;
  size_t base = (size_t)row * ND;
  float sq = 0.f;
#pragma unroll
  for (int c = 0; c < 4; ++c) {
    size_t o = base + c * 256 + lane * 4;
    float4 v = *reinterpret_cast<const float4*>(x + o);
    ushort4 ob;
    ob.x = f2bf(v.x); ob.y = f2bf(v.y); ob.z = f2bf(v.z); ob.w = f2bf(v.w);
    *reinterpret_cast<ushort4*>(xb + o) = ob;
    sq += v.x * v.x + v.y * v.y + v.z * v.z + v.w * v.w;
  }
#pragma unroll
  for (int off = 32; off; off >>= 1) sq += __shfl_xor(sq, off);
  if (lane == 0) {
    DGa[row] = sq;
    IXa[row] = 1.0f / sqrtf(sq);   // inf if 0 -> forces slow path everywhere
  }
}

// ---- Y[rr,d] = sum_{s<=rr} x[s,d]  (inclusive prefix, fp32 accum -> bf16) ----
// thread per (b,d): 8192 threads
__global__ __launch_bounds__(256) void k_ypfx(const unsigned short* __restrict__ xb,
                                              unsigned short* __restrict__ yb) {
  int gid = blockIdx.x * 256 + threadIdx.x;   // 0..8191
  int b = gid >> 10;
  int d = gid & 1023;
  const unsigned short* xr = xb + ((size_t)b << 18) + d;
  unsigned short* yr = yb + ((size_t)b << 18) + d;
  float run = 0.f;
  for (int s = 0; s < NS; ++s) {
    run += bf2f(xr[(size_t)s * ND]);
    yr[(size_t)s * ND] = f2bf(run);
  }
}

// ---- C[r,t] = Y_r . x_t  (bf16 MFMA, K-split 2, partials Cp0/Cp1) ----
// wave job: 32x32 tile of (rr,t), rr = r-1
__global__ __launch_bounds__(256) void k_gemmC(const unsigned short* __restrict__ yb,
                                               const unsigned short* __restrict__ xb,
                                               float* __restrict__ cp) {
  int gw = ((blockIdx.x << 8) + threadIdx.x) >> 6;  // 0..1023
  int lane = threadIdx.x & 63;
  int b  = gw & 7;
  int mt = (gw >> 3) & 7;
  int nt = (gw >> 6) & 7;
  int ks = (gw >> 9) & 1;
  const unsigned short* Ab = yb + ((size_t)b << 18) + ((size_t)(mt << 5) << 10);
  const unsigned short* Bb = xb + ((size_t)b << 18) + ((size_t)(nt << 5) << 10);
  int lr = lane & 15;
  int lk = (lane >> 4) << 3;
  f32x4 acc00 = {0.f,0.f,0.f,0.f}, acc01 = {0.f,0.f,0.f,0.f};
  f32x4 acc10 = {0.f,0.f,0.f,0.f}, acc11 = {0.f,0.f,0.f,0.f};
  int kbase = (ks << 9) + lk;
#pragma unroll 2
  for (int kk = 0; kk < 512; kk += 32) {
    int ko = kbase + kk;
    short8 a0  = *reinterpret_cast<const short8*>(Ab + ((size_t)lr << 10) + ko);
    short8 a1  = *reinterpret_cast<const short8*>(Ab + ((size_t)(16 + lr) << 10) + ko);
    short8 bb0 = *reinterpret_cast<const short8*>(Bb + ((size_t)lr << 10) + ko);
    short8 bb1 = *reinterpret_cast<const short8*>(Bb + ((size_t)(16 + lr) << 10) + ko);
    acc00 = __builtin_amdgcn_mfma_f32_16x16x32_bf16(a0, bb0, acc00, 0, 0, 0);
    acc01 = __builtin_amdgcn_mfma_f32_16x16x32_bf16(a0, bb1, acc01, 0, 0, 0);
    acc10 = __builtin_amdgcn_mfma_f32_16x16x32_bf16(a1, bb0, acc10, 0, 0, 0);
    acc11 = __builtin_amdgcn_mfma_f32_16x16x32_bf16(a1, bb1, acc11, 0, 0, 0);
  }
  // C/D layout: col = lane&15, row = (lane>>4)*4 + j   [measured m89]
  float* G = cp + (size_t)ks * (NB * NS * NS) + ((size_t)b << 16);
  int r0 = (mt << 5) + ((lane >> 4) << 2);
  int c0 = (nt << 5) + lr;
#pragma unroll
  for (int j = 0; j < 4; ++j) {
    G[(r0 + j) * NS + c0]           = acc00[j];
    G[(r0 + j) * NS + c0 + 16]      = acc01[j];
    G[(r0 + 16 + j) * NS + c0]      = acc10[j];
    G[(r0 + 16 + j) * NS + c0 + 16] = acc11[j];
  }
}

// ---- reduce partials -> C (257 rows, row 0 = 0), S2[r,c] = prefix of C row ----
// one wave per (b,r): 2056 waves
__global__ __launch_bounds__(256) void k_scan(const float* __restrict__ cp,
                                              float* __restrict__ C, float* __restrict__ S2) {
  int id = blockIdx.x * 4 + (threadIdx.x >> 6);   // 0..2055
  int lane = threadIdx.x & 63;
  int b = id / 257;
  int r = id - b * 257;
  float* Crow = C + ((size_t)b * 257 + r) * NS;
  float* Srow = S2 + ((size_t)b * 257 + r) * 257;
  const float* p0 = cp + (((size_t)b << 8) + (r - 1)) * NS;
  const float* p1 = p0 + (size_t)NB * NS * NS;
  if (lane == 0) Srow[0] = 0.f;
  float run = 0.f;
  for (int c0 = 0; c0 < NS; c0 += 64) {
    float v = 0.f;
    if (r > 0) v = p0[c0 + lane] + p1[c0 + lane];
    Crow[c0 + lane] = v;
#pragma unroll
    for (int off = 1; off < 64; off <<= 1) {
      float n = __shfl_up(v, off);
      if (lane >= off) v += n;
    }
    Srow[c0 + lane + 1] = run + v;
    run += __shfl(v, 63);
  }
}

// ---- tropical GEMM: worst[i,j] = min_t (W[j+1,t]-W[i,t]) / sn(i,j) ----
// grid covers ALL 32x64 tiles (8b x 8it x 4jt); invalid tiles/cells write 0
__global__ __launch_bounds__(256) void k_trop(const float* __restrict__ C,
                                              const float* __restrict__ S2,
                                              const float* __restrict__ IXa,
                                              const float* __restrict__ DGa,
                                              float* __restrict__ out) {
  __shared__ float As[64][36];   // As[tt][ii]
  __shared__ float Bs[64][68];   // Bs[tt][jj]
  __shared__ float wred[4];
  int blk = blockIdx.x;
  int b = blk >> 5;
  int tix = blk & 31;
  int i0 = (tix >> 2) << 5;
  int j0 = (tix & 3) << 6;
  int tid = threadIdx.x;
  float* outb = out + ((size_t)b << 16);

  if (i0 >= j0 + 63) {           // fully-invalid tile: zero-fill
    float4 z = {0.f, 0.f, 0.f, 0.f};
    float* p = outb + (size_t)(i0 + (tid >> 3)) * NS + j0 + ((tid & 7) << 3);
    reinterpret_cast<float4*>(p)[0] = z;
    reinterpret_cast<float4*>(p)[1] = z;
    return;
  }

  const float* Cb = C + (size_t)b * 257 * NS;
  const float* IXb = IXa + b * NS;

  // per-batch wmax (block reduce)
  float wv0 = IXb[tid];
#pragma unroll
  for (int off = 32; off; off >>= 1) wv0 = fmaxf(wv0, __shfl_xor(wv0, off));
  if ((tid & 63) == 0) wred[tid >> 6] = wv0;
  __syncthreads();
  float wmb = fmaxf(fmaxf(wred[0], wred[1]), fmaxf(wred[2], wred[3]));

  int ii0 = (tid >> 4) << 1;     // 0,2,...,30
  int jj0 = (tid & 15) << 2;     // 0,4,...,60
  float acc[8];
#pragma unroll
  for (int k = 0; k < 8; ++k) acc[k] = BIGF;

  int rA = tid >> 4;             // 0..15
  int c4 = (tid & 15) << 2;      // 0..60

  for (int t0 = i0 & ~63; t0 < j0 + 64; t0 += 64) {
    __syncthreads();
    float4 wv = *reinterpret_cast<const float4*>(IXb + t0 + c4);
#pragma unroll
    for (int p = 0; p < 2; ++p) {      // A: rows i0..i0+31
      int r = i0 + p * 16 + rA;
      float4 v = *reinterpret_cast<const float4*>(Cb + (size_t)r * NS + t0 + c4);
      As[c4 + 0][p * 16 + rA] = v.x * wv.x;
      As[c4 + 1][p * 16 + rA] = v.y * wv.y;
      As[c4 + 2][p * 16 + rA] = v.z * wv.z;
      As[c4 + 3][p * 16 + rA] = v.w * wv.w;
    }
#pragma unroll
    for (int p = 0; p < 4; ++p) {      // B: rows j0+1..j0+64
      int r = j0 + 1 + p * 16 + rA;
      float4 v = *reinterpret_cast<const float4*>(Cb + (size_t)r * NS + t0 + c4);
      Bs[c4 + 0][p * 16 + rA] = v.x * wv.x;
      Bs[c4 + 1][p * 16 + rA] = v.y * wv.y;
      Bs[c4 + 2][p * 16 + rA] = v.z * wv.z;
      Bs[c4 + 3][p * 16 + rA] = v.w * wv.w;
    }
    __syncthreads();

    int thA = i0 + ii0 - t0;   // a[k] valid iff tt >= thA + k
    int thB = j0 + jj0 - t0;   // b[l] valid iff tt <= thB + l
    if (thA <= -1 && thB >= 63) {
#pragma unroll 4
      for (int tt = 0; tt < 64; ++tt) {
        float2 a = *reinterpret_cast<const float2*>(&As[tt][ii0]);
        float4 bv = *reinterpret_cast<const float4*>(&Bs[tt][jj0]);
        acc[0] = fminf(acc[0], bv.x - a.x);
        acc[1] = fminf(acc[1], bv.y - a.x);
        acc[2] = fminf(acc[2], bv.z - a.x);
        acc[3] = fminf(acc[3], bv.w - a.x);
        acc[4] = fminf(acc[4], bv.x - a.y);
        acc[5] = fminf(acc[5], bv.y - a.y);
        acc[6] = fminf(acc[6], bv.z - a.y);
        acc[7] = fminf(acc[7], bv.w - a.y);
      }
    } else {
#pragma unroll 4
      for (int tt = 0; tt < 64; ++tt) {
        float2 a = *reinterpret_cast<const float2*>(&As[tt][ii0]);
        float4 bv = *reinterpret_cast<const float4*>(&Bs[tt][jj0]);
        float a0 = (tt >= thA)     ? a.x  : -BIGF;
        float a1 = (tt >= thA + 1) ? a.y  : -BIGF;
        float b0 = (tt <= thB)     ? bv.x :  BIGF;
        float b1 = (tt <= thB + 1) ? bv.y :  BIGF;
        float b2 = (tt <= thB + 2) ? bv.z :  BIGF;
        float b3 = (tt <= thB + 3) ? bv.w :  BIGF;
        acc[0] = fminf(acc[0], b0 - a0);
        acc[1] = fminf(acc[1], b1 - a0);
        acc[2] = fminf(acc[2], b2 - a0);
        acc[3] = fminf(acc[3], b3 - a0);
        acc[4] = fminf(acc[4], b0 - a1);
        acc[5] = fminf(acc[5], b1 - a1);
        acc[6] = fminf(acc[6], b2 - a1);
        acc[7] = fminf(acc[7], b3 - a1);
      }
    }
  }

  // epilogue: res = min_num / sn, 0 for invalid cells; vector stores cover tile
  const float* S2b = S2 + (size_t)b * 257 * 257;
  const float* DGb = DGa + b * NS;
#pragma unroll
  for (int k = 0; k < 2; ++k) {
    int i = i0 + ii0 + k;
    float o4[4];
    float s2ii = S2b[(size_t)i * 257 + i];
#pragma unroll
    for (int l = 0; l < 4; ++l) {
      int j = j0 + jj0 + l;
      float res = 0.f;
      if (i >= 1 && j > i) {
        float s2jj = S2b[(size_t)(j + 1) * 257 + (j + 1)];
        float s2ij = S2b[(size_t)i * 257 + (j + 1)];
        float s2ji = S2b[(size_t)(j + 1) * 257 + i];
        float ssq = (s2jj - s2ij) - (s2ji - s2ii);
        float sn = sqrtf(fmaxf(ssq, 0.f));
        float win = (float)(j - i + 1);
        if (sn >= EPSF * win * wmb) {
          res = acc[k * 4 + l] / sn;               // fast path: EPS never binds
        } else {
          float mn = sn / win;
          float m = BIGF;
          const float* r2 = Cb + (size_t)(j + 1) * NS;
          const float* r1 = Cb + (size_t)i * NS;
          for (int t = i; t <= j; ++t) {
            float num = r2[t] - r1[t];
            float xn = sqrtf(fmaxf(DGb[t], 0.f));
            float den = fmaxf(mn * xn, EPSF);
            m = fminf(m, num / win / den);
          }
          res = m;
        }
      }
      o4[l] = res;
    }
    float4 st = {o4[0], o4[1], o4[2], o4[3]};
    *reinterpret_cast<float4*>(outb + (size_t)i * NS + j0 + jj0) = st;
  }
}

extern "C" void kernel_launch(void* const* d_in, const int* in_sizes, int n_in,
                              void* d_out, int out_size, void* d_ws, size_t ws_size,
                              hipStream_t stream) {
  (void)in_sizes; (void)n_in; (void)ws_size; (void)out_size;
  const float* x = (const float*)d_in[0];
  float* out = (float*)d_out;
  char* ws = (char*)d_ws;
  unsigned short* Xb = (unsigned short*)(ws);                 //  4,194,304 B
  unsigned short* Yb = (unsigned short*)(ws + 4194304);       //  4,194,304 B
  float* Cp  = (float*)(ws + 8388608);                        //  4,194,304 B (2 x 8 x 256 x 256)
  float* C   = (float*)(ws + 12582912);                       //  2,105,344 B (8 x 257 x 256)
  float* S2  = (float*)(ws + 14688256);                       //  2,113,568 B (8 x 257 x 257)
  float* DGa = (float*)(ws + 16801824);                       //  8,192 B
  float* IXa = (float*)(ws + 16810016);                       //  8,192 B

  k_convert<<<512, 256, 0, stream>>>(x, Xb, DGa, IXa);
  k_ypfx<<<32, 256, 0, stream>>>(Xb, Yb);
  k_gemmC<<<256, 256, 0, stream>>>(Yb, Xb, Cp);
  k_scan<<<514, 256, 0, stream>>>(Cp, C, S2);
  k_trop<<<256, 256, 0, stream>>>(C, S2, IXa, DGa, out);
}